// Round 5
// baseline (672.886 us; speedup 1.0000x reference)
//
#include <hip/hip_runtime.h>
#include <math.h>

typedef unsigned short u16;
typedef unsigned int u32;

// ---- problem constants ----
constexpr int Bb = 4, Ll = 2048, DM = 1024, DI = 2048, DS = 16, DTR = 64, KC = 4;
constexpr int M = Bb * Ll;            // 8192 rows
constexpr int NPAD = 128;             // padded x_dbl width (64 + 2*16 = 96 -> 128)
constexpr int NCHUNK = 16;            // scan chunks
constexpr int LC = Ll / NCHUNK;       // 128 steps per chunk

// ---- bf16 helpers on raw u16 ----
__device__ __forceinline__ float b2f(u16 u) {
    return __uint_as_float(((u32)u) << 16);
}
__device__ __forceinline__ u16 f2b(float f) {
    u32 x = __float_as_uint(f);
    u32 r = (x + 0x7fffu + ((x >> 16) & 1u)) >> 16;   // round-to-nearest-even
    return (u16)r;
}

typedef __attribute__((ext_vector_type(8))) short short8;
typedef __attribute__((ext_vector_type(4))) float floatx4;

// async global->LDS, 16B per lane; LDS dest = wave-uniform base + lane*16
__device__ __forceinline__ void gload16(const u16* g, u16* l) {
    __builtin_amdgcn_global_load_lds(
        (const __attribute__((address_space(1))) void*)g,
        (__attribute__((address_space(3))) void*)l,
        16, 0, 0);
}

// =====================================================================
// C(MxN) = A(MxK) * B(NxK)^T, bf16 in, fp32 MFMA acc.  m97 structure:
// 128x128 block tile, BK=32, LDS-staged via global_load_lds width=16,
// 4 waves each computing 64x64 (4x4 MFMA 16x16x32 frags).
// OUTM: 0 = bf16 store, 1 = fp32 store, 2 = softplus(acc + bias[n]) bf16,
//       3 = bf16 store + fp32 sideband of cols [64,96) into aux (ld 32)
// =====================================================================
template<int OUTM>
__global__ __launch_bounds__(256) void gemm_bt(
    const u16* __restrict__ A, const u16* __restrict__ Bm,
    void* __restrict__ Cv, const float* __restrict__ bias,
    float* __restrict__ aux,
    int K, int lda, int ldb, int ldc)
{
    __shared__ alignas(16) u16 ldsA[128 * 32];
    __shared__ alignas(16) u16 ldsB[128 * 32];

    const int lane = threadIdx.x & 63;
    const int wave = threadIdx.x >> 6;
    const int wr = wave >> 1, wc = wave & 1;
    const int m0 = blockIdx.y * 128;
    const int n0 = blockIdx.x * 128;

    const int srow = wave * 32 + (lane >> 2);           // staging row (+t*16)
    const int skc  = (lane & 3) * 8;                    // staging k offset
    const u16* Ag = A + (size_t)(m0 + srow) * lda + skc;
    const u16* Bg = Bm + (size_t)(n0 + srow) * ldb + skc;
    u16* lA = &ldsA[wave * 1024];                       // wave-uniform base
    u16* lB = &ldsB[wave * 1024];

    const int r16 = lane & 15;
    const int quad = lane >> 4;
    const u16* arow = &ldsA[(wr * 64 + r16) * 32 + quad * 8];
    const u16* brow = &ldsB[(wc * 64 + r16) * 32 + quad * 8];

    floatx4 acc[4][4] = {};

    for (int k0 = 0; k0 < K; k0 += 32) {
        gload16(Ag + k0,                    lA);
        gload16(Ag + k0 + (size_t)16 * lda, lA + 512);
        gload16(Bg + k0,                    lB);
        gload16(Bg + k0 + (size_t)16 * ldb, lB + 512);
        __syncthreads();

        short8 af[4], bf[4];
#pragma unroll
        for (int i = 0; i < 4; i++) af[i] = *(const short8*)(arow + i * 16 * 32);
#pragma unroll
        for (int j = 0; j < 4; j++) bf[j] = *(const short8*)(brow + j * 16 * 32);
#pragma unroll
        for (int i = 0; i < 4; i++)
#pragma unroll
            for (int j = 0; j < 4; j++)
                acc[i][j] = __builtin_amdgcn_mfma_f32_16x16x32_bf16(
                    af[i], bf[j], acc[i][j], 0, 0, 0);
        __syncthreads();
    }

    // D layout: col = lane&15, row = quad*4 + r   [verified m89/m91]
    const int mw = m0 + wr * 64;
    const int nw = n0 + wc * 64;
    const int rb = quad * 4;
#pragma unroll
    for (int i = 0; i < 4; i++) {
#pragma unroll
        for (int j = 0; j < 4; j++) {
            const int n = nw + j * 16 + r16;
#pragma unroll
            for (int r = 0; r < 4; r++) {
                const int m = mw + i * 16 + rb + r;
                float v = acc[i][j][r];
                if (OUTM == 2) {
                    v += bias[n];
                    v = (v > 20.f) ? v : log1pf(__expf(v));
                }
                if (OUTM == 1)
                    ((float*)Cv)[(size_t)m * ldc + n] = v;
                else
                    ((u16*)Cv)[(size_t)m * ldc + n] = f2b(v);
                if (OUTM == 3 && n >= 64 && n < 96)
                    aux[(size_t)m * 32 + (n - 64)] = v;
            }
        }
    }
}

// =====================================================================
__global__ __launch_bounds__(256) void cvt_f2b(
    const float* __restrict__ in, u16* __restrict__ out, int n)
{
    int i = blockIdx.x * blockDim.x + threadIdx.x;
    if (i < n) out[i] = f2b(in[i]);
}

__global__ __launch_bounds__(256) void pad_wx(
    const float* __restrict__ W_x, u16* __restrict__ out)
{
    int idx = blockIdx.x * blockDim.x + threadIdx.x;   // over 128*2048
    int r = idx >> 11;
    int c = idx & 2047;
    out[idx] = (r < 96) ? f2b(W_x[r * 2048 + c]) : (u16)0;
}

// =====================================================================
// Depthwise causal conv (K=4) + SiLU.
// =====================================================================
__global__ __launch_bounds__(256) void conv_silu(
    const u16* __restrict__ xr, const float* __restrict__ conv_w,
    const float* __restrict__ conv_b, u16* __restrict__ xs)
{
    int idx = blockIdx.x * blockDim.x + threadIdx.x;   // over M*DI
    int m = idx >> 11;
    int d = idx & 2047;
    int l = m & (Ll - 1);

    float acc = conv_b[d];
#pragma unroll
    for (int k = 0; k < KC; k++) {
        int li = l - (KC - 1) + k;
        if (li >= 0)
            acc += b2f(xr[(size_t)(m - (KC - 1) + k) * DI + d]) * conv_w[d * KC + k];
    }
    float s = acc / (1.f + __expf(-acc));
    xs[(size_t)m * DI + d] = f2b(s);
}

// =====================================================================
// Chunked selective scan, state-split: 2 threads per (channel, chunk),
// 8 states each.  Fast path (A_log = log(1..16) detected wave-uniformly):
// a_s = exp(dt*ad0)^(s+1) -> 2 exps + mul chain instead of 8 exps.
// B/C read as fp32 from the bcf sideband (no bf16 unpack).
// =====================================================================
__global__ __launch_bounds__(256) void scan_p1(
    const u16* __restrict__ dtb, const u16* __restrict__ xs,
    const float* __restrict__ bcf, const float* __restrict__ A_log,
    float* __restrict__ scr_P, float* __restrict__ scr_hend)
{
    const int t = threadIdx.x;
    const int d = blockIdx.x * 128 + (t >> 1);
    const int hf = t & 1;
    const int b = blockIdx.y;
    const int c = blockIdx.z;

    const float ad0 = -__expf(A_log[0]);
    float adl[8];
    bool fast = true;
#pragma unroll
    for (int j = 0; j < 8; j++) {
        int s = hf * 8 + j;
        float av = -__expf(A_log[s]);
        adl[j] = av;
        float kr = (float)(s + 1);
        if (fabsf(av / ad0 - kr) > 1e-4f * kr) fast = false;
    }

    const int m0 = b * Ll + c * LC;
    const u16* dt_p = dtb + (size_t)m0 * DI + d;
    const u16* xs_p = xs + (size_t)m0 * DI + d;
    const float* bc_p = bcf + (size_t)m0 * 32 + hf * 8;

    float h[8] = {};
    float P[8];
#pragma unroll
    for (int j = 0; j < 8; j++) P[j] = 1.f;

    if (fast) {
        for (int l = 0; l < LC; l++) {
            float dtv = b2f(dt_p[0]);
            float xv  = b2f(xs_p[0]);
            floatx4 B0 = *(const floatx4*)(bc_p);
            floatx4 B1 = *(const floatx4*)(bc_p + 4);
            float bx = dtv * xv;
            float e0 = __expf(dtv * ad0);
            float a  = __expf(dtv * adl[0]);
#pragma unroll
            for (int j = 0; j < 8; j++) {
                float Bv = (j < 4) ? B0[j] : B1[j - 4];
                h[j] = a * h[j] + bx * Bv;
                P[j] *= a;
                a *= e0;
            }
            dt_p += DI; xs_p += DI; bc_p += 32;
        }
    } else {
        for (int l = 0; l < LC; l++) {
            float dtv = b2f(dt_p[0]);
            float xv  = b2f(xs_p[0]);
            floatx4 B0 = *(const floatx4*)(bc_p);
            floatx4 B1 = *(const floatx4*)(bc_p + 4);
            float bx = dtv * xv;
#pragma unroll
            for (int j = 0; j < 8; j++) {
                float Bv = (j < 4) ? B0[j] : B1[j - 4];
                float a = __expf(dtv * adl[j]);
                h[j] = a * h[j] + bx * Bv;
                P[j] *= a;
            }
            dt_p += DI; xs_p += DI; bc_p += 32;
        }
    }

    const size_t base = ((size_t)(b * NCHUNK + c) * DI + d) * DS + hf * 8;
    floatx4 p0 = {P[0], P[1], P[2], P[3]}, p1 = {P[4], P[5], P[6], P[7]};
    floatx4 h0 = {h[0], h[1], h[2], h[3]}, h1 = {h[4], h[5], h[6], h[7]};
    *(floatx4*)(scr_P + base)        = p0;
    *(floatx4*)(scr_P + base + 4)    = p1;
    *(floatx4*)(scr_hend + base)     = h0;
    *(floatx4*)(scr_hend + base + 4) = h1;
}

__global__ __launch_bounds__(256) void scan_p2(
    float* __restrict__ scr_P, const float* __restrict__ scr_hend)
{
    const int t = blockIdx.x * 256 + threadIdx.x;   // (b, d, s)
    const int s = t & 15;
    const int d = (t >> 4) & (DI - 1);
    const int b = t >> 15;

    float hin = 0.f;
    for (int c = 0; c < NCHUNK; c++) {
        const size_t base = ((size_t)(b * NCHUNK + c) * DI + d) * DS + s;
        float p = scr_P[base];
        float he = scr_hend[base];
        scr_P[base] = hin;
        hin = p * hin + he;
    }
}

__global__ __launch_bounds__(256) void scan_p3(
    const u16* __restrict__ dtb, const u16* xs, const float* __restrict__ bcf,
    const u16* __restrict__ z, const float* __restrict__ scr_hin,
    const float* __restrict__ A_log, const float* __restrict__ Dvec,
    u16* yg)
{
    const int t = threadIdx.x;
    const int d = blockIdx.x * 128 + (t >> 1);
    const int hf = t & 1;
    const int b = blockIdx.y;
    const int c = blockIdx.z;

    const float ad0 = -__expf(A_log[0]);
    float adl[8];
    bool fast = true;
#pragma unroll
    for (int j = 0; j < 8; j++) {
        int s = hf * 8 + j;
        float av = -__expf(A_log[s]);
        adl[j] = av;
        float kr = (float)(s + 1);
        if (fabsf(av / ad0 - kr) > 1e-4f * kr) fast = false;
    }
    const float Dd = Dvec[d];

    const int m0 = b * Ll + c * LC;
    const u16* dt_p = dtb + (size_t)m0 * DI + d;
    const u16* xs_p = xs + (size_t)m0 * DI + d;
    const u16* z_p  = z + (size_t)m0 * DI + d;
    const float* bc_p = bcf + (size_t)m0 * 32 + hf * 8;
    u16* yg_p = yg + (size_t)m0 * DI + d;

    float h[8];
    const size_t base = ((size_t)(b * NCHUNK + c) * DI + d) * DS + hf * 8;
    {
        floatx4 h0 = *(const floatx4*)(scr_hin + base);
        floatx4 h1 = *(const floatx4*)(scr_hin + base + 4);
#pragma unroll
        for (int j = 0; j < 4; j++) { h[j] = h0[j]; h[j + 4] = h1[j]; }
    }

    if (fast) {
        for (int l = 0; l < LC; l++) {
            float dtv = b2f(dt_p[0]);
            float xv  = b2f(xs_p[0]);
            floatx4 B0 = *(const floatx4*)(bc_p);
            floatx4 B1 = *(const floatx4*)(bc_p + 4);
            floatx4 C0 = *(const floatx4*)(bc_p + 16);
            floatx4 C1 = *(const floatx4*)(bc_p + 20);
            float bx = dtv * xv;
            float e0 = __expf(dtv * ad0);
            float a  = __expf(dtv * adl[0]);
            float y = 0.f;
#pragma unroll
            for (int j = 0; j < 8; j++) {
                float Bv = (j < 4) ? B0[j] : B1[j - 4];
                float Cv = (j < 4) ? C0[j] : C1[j - 4];
                h[j] = a * h[j] + bx * Bv;
                y += h[j] * Cv;
                a *= e0;
            }
            float p = y + __shfl_xor(y, 1);
            if (hf == 0) {
                float yt = p + Dd * xv;
                float zv = b2f(z_p[0]);
                float g = zv / (1.f + __expf(-zv));
                yg_p[0] = f2b(yt * g);
            }
            dt_p += DI; xs_p += DI; z_p += DI; bc_p += 32; yg_p += DI;
        }
    } else {
        for (int l = 0; l < LC; l++) {
            float dtv = b2f(dt_p[0]);
            float xv  = b2f(xs_p[0]);
            floatx4 B0 = *(const floatx4*)(bc_p);
            floatx4 B1 = *(const floatx4*)(bc_p + 4);
            floatx4 C0 = *(const floatx4*)(bc_p + 16);
            floatx4 C1 = *(const floatx4*)(bc_p + 20);
            float bx = dtv * xv;
            float y = 0.f;
#pragma unroll
            for (int j = 0; j < 8; j++) {
                float Bv = (j < 4) ? B0[j] : B1[j - 4];
                float Cv = (j < 4) ? C0[j] : C1[j - 4];
                float a = __expf(dtv * adl[j]);
                h[j] = a * h[j] + bx * Bv;
                y += h[j] * Cv;
            }
            float p = y + __shfl_xor(y, 1);
            if (hf == 0) {
                float yt = p + Dd * xv;
                float zv = b2f(z_p[0]);
                float g = zv / (1.f + __expf(-zv));
                yg_p[0] = f2b(yt * g);
            }
            dt_p += DI; xs_p += DI; z_p += DI; bc_p += 32; yg_p += DI;
        }
    }
}

// =====================================================================
extern "C" void kernel_launch(void* const* d_in, const int* in_sizes, int n_in,
                              void* d_out, int out_size, void* d_ws, size_t ws_size,
                              hipStream_t stream)
{
    const float* x      = (const float*)d_in[0];   // (B,L,DM)
    const float* W_in   = (const float*)d_in[1];   // (2*DI, DM)
    const float* conv_w = (const float*)d_in[2];   // (DI, KC)
    const float* conv_b = (const float*)d_in[3];   // (DI,)
    const float* A_log  = (const float*)d_in[4];   // (DS,)
    const float* Dvec   = (const float*)d_in[5];   // (DI,)
    const float* W_x    = (const float*)d_in[6];   // (96, DI)
    const float* W_dt   = (const float*)d_in[7];   // (DI, DTR)
    const float* b_dt   = (const float*)d_in[8];   // (DI,)
    const float* W_out  = (const float*)d_in[9];   // (DM, DI)

    // ---- workspace arena (bf16 u16 elements), ~133 MB total ----
    u16* ws = (u16*)d_ws;
    u16* xr    = ws;                 ws += (size_t)M * DI;       // reused as dtb
    u16* z     = ws;                 ws += (size_t)M * DI;
    u16* xs    = ws;                 ws += (size_t)M * DI;       // yg in-place
    u16* xbf   = ws;                 ws += (size_t)M * DM;       // reused as scan scratch
    u16* wibf  = ws;                 ws += (size_t)2 * DI * DM;  // full W_in; reused as bcf
    u16* wxp   = ws;                 ws += (size_t)NPAD * DI;
    u16* wdtb  = ws;                 ws += (size_t)DI * DTR;
    u16* woutb = ws;                 ws += (size_t)DM * DI;
    u16* xdbl  = ws;                 ws += (size_t)M * NPAD;
    u16* dtb   = xr;                 // alias (xr dead after conv)
    u16* yg    = xs;                 // in-place (each (m,d) owned by one pair)
    float* scr_P    = (float*)xbf;   // scan scratch reuses dead xbf (16.78 MB)
    float* scr_hend = scr_P + (size_t)Bb * NCHUNK * DI * DS;
    float* bcf      = (float*)wibf;  // fp32 B/C sideband (1.05 MB, wibf dead)

    // 0) conversions for GEMM operands
    cvt_f2b<<<(M * DM) / 256, 256, 0, stream>>>(x, xbf, M * DM);
    cvt_f2b<<<(2 * DI * DM) / 256, 256, 0, stream>>>(W_in, wibf, 2 * DI * DM);
    pad_wx<<<(NPAD * DI) / 256, 256, 0, stream>>>(W_x, wxp);
    cvt_f2b<<<(DI * DTR) / 256, 256, 0, stream>>>(W_dt, wdtb, DI * DTR);
    cvt_f2b<<<(DM * DI) / 256, 256, 0, stream>>>(W_out, woutb, DM * DI);

    // 1a) xr = x @ W_in[0:DI]^T   (8192 x 2048, K=1024)
    gemm_bt<0><<<dim3(DI / 128, M / 128), 256, 0, stream>>>(
        xbf, wibf, xr, nullptr, nullptr, DM, DM, DM, DI);
    // 1b) z = x @ W_in[DI:2DI]^T
    gemm_bt<0><<<dim3(DI / 128, M / 128), 256, 0, stream>>>(
        xbf, wibf + (size_t)DI * DM, z, nullptr, nullptr, DM, DM, DM, DI);

    // 2) conv + silu -> xs
    conv_silu<<<(M * DI) / 256, 256, 0, stream>>>(xr, conv_w, conv_b, xs);

    // 3) x_dbl = xs @ wxp^T (8192 x 128, K=2048) + fp32 B/C sideband -> bcf
    gemm_bt<3><<<dim3(NPAD / 128, M / 128), 256, 0, stream>>>(
        xs, wxp, xdbl, nullptr, bcf, DI, DI, DI, NPAD);

    // 4) dt = softplus(x_dbl[:, :64] @ W_dt^T + b_dt)   (8192 x 2048, K=64)
    gemm_bt<2><<<dim3(DI / 128, M / 128), 256, 0, stream>>>(
        xdbl, wdtb, dtb, b_dt, nullptr, DTR, NPAD, DTR, DI);

    // 5) chunked scan, state-split (2 threads/channel-chunk)
    scan_p1<<<dim3(DI / 128, Bb, NCHUNK), 256, 0, stream>>>(
        dtb, xs, bcf, A_log, scr_P, scr_hend);
    scan_p2<<<(Bb * DI * DS) / 256, 256, 0, stream>>>(scr_P, scr_hend);
    scan_p3<<<dim3(DI / 128, Bb, NCHUNK), 256, 0, stream>>>(
        dtb, xs, bcf, z, scr_P, A_log, Dvec, yg);

    // 6) out = yg @ W_out^T   (8192 x 1024, K=2048), fp32 store
    gemm_bt<1><<<dim3(DM / 128, M / 128), 256, 0, stream>>>(
        yg, woutb, d_out, nullptr, nullptr, DI, DI, DI, DM);
}

// Round 6
// 579.659 us; speedup vs baseline: 1.1608x; 1.1608x over previous
//
#include <hip/hip_runtime.h>
#include <math.h>

typedef unsigned short u16;
typedef unsigned int u32;

// ---- problem constants ----
constexpr int Bb = 4, Ll = 2048, DM = 1024, DI = 2048, DS = 16, DTR = 64, KC = 4;
constexpr int M = Bb * Ll;            // 8192 rows
constexpr int NPAD = 128;             // padded x_dbl width (64 + 2*16 = 96 -> 128)
constexpr int NCHUNK = 16;            // scan chunks
constexpr int LC = Ll / NCHUNK;       // 128 steps per chunk
constexpr int LDXZ = 4096;            // xz row stride (xr|z interleaved)

// ---- bf16 helpers on raw u16 ----
__device__ __forceinline__ float b2f(u16 u) {
    return __uint_as_float(((u32)u) << 16);
}
__device__ __forceinline__ u16 f2b(float f) {
    u32 x = __float_as_uint(f);
    u32 r = (x + 0x7fffu + ((x >> 16) & 1u)) >> 16;   // round-to-nearest-even
    return (u16)r;
}

typedef __attribute__((ext_vector_type(8))) short short8;
typedef __attribute__((ext_vector_type(4))) float floatx4;

// async global->LDS, 16B per lane; LDS dest = wave-uniform base + lane*16
__device__ __forceinline__ void gload16(const u16* g, u16* l) {
    __builtin_amdgcn_global_load_lds(
        (const __attribute__((address_space(1))) void*)g,
        (__attribute__((address_space(3))) void*)l,
        16, 0, 0);
}

// a^(s+1) for s=0..15 from base a, tree form (15 muls, depth 4)
__device__ __forceinline__ void pow_tree(float a, float* aa) {
    float a2 = a * a, a4 = a2 * a2, a8 = a4 * a4;
    aa[0] = a;        aa[1] = a2;       aa[2] = a * a2;   aa[3] = a4;
    aa[4] = a * a4;   aa[5] = a2 * a4;  aa[6] = aa[2] * a4; aa[7] = a8;
    aa[8] = a * a8;   aa[9] = a2 * a8;  aa[10] = aa[2] * a8; aa[11] = a4 * a8;
    aa[12] = aa[4] * a8; aa[13] = aa[5] * a8; aa[14] = aa[6] * a8; aa[15] = a8 * a8;
}

// =====================================================================
// C(MxN) = A(MxK) * B(NxK)^T, bf16 in, fp32 MFMA acc.  m97 structure.
// OUTM: 0 = bf16 store, 1 = fp32 store, 2 = softplus(acc + bias[n]) bf16,
//       3 = bf16 store + fp32 sideband of cols [64,96) into aux (ld 32)
// =====================================================================
template<int OUTM>
__global__ __launch_bounds__(256) void gemm_bt(
    const u16* __restrict__ A, const u16* __restrict__ Bm,
    void* __restrict__ Cv, const float* __restrict__ bias,
    float* __restrict__ aux,
    int K, int lda, int ldb, int ldc)
{
    __shared__ alignas(16) u16 ldsA[128 * 32];
    __shared__ alignas(16) u16 ldsB[128 * 32];

    const int lane = threadIdx.x & 63;
    const int wave = threadIdx.x >> 6;
    const int wr = wave >> 1, wc = wave & 1;
    const int m0 = blockIdx.y * 128;
    const int n0 = blockIdx.x * 128;

    const int srow = wave * 32 + (lane >> 2);
    const int skc  = (lane & 3) * 8;
    const u16* Ag = A + (size_t)(m0 + srow) * lda + skc;
    const u16* Bg = Bm + (size_t)(n0 + srow) * ldb + skc;
    u16* lA = &ldsA[wave * 1024];
    u16* lB = &ldsB[wave * 1024];

    const int r16 = lane & 15;
    const int quad = lane >> 4;
    const u16* arow = &ldsA[(wr * 64 + r16) * 32 + quad * 8];
    const u16* brow = &ldsB[(wc * 64 + r16) * 32 + quad * 8];

    floatx4 acc[4][4] = {};

    for (int k0 = 0; k0 < K; k0 += 32) {
        gload16(Ag + k0,                    lA);
        gload16(Ag + k0 + (size_t)16 * lda, lA + 512);
        gload16(Bg + k0,                    lB);
        gload16(Bg + k0 + (size_t)16 * ldb, lB + 512);
        __syncthreads();

        short8 af[4], bf[4];
#pragma unroll
        for (int i = 0; i < 4; i++) af[i] = *(const short8*)(arow + i * 16 * 32);
#pragma unroll
        for (int j = 0; j < 4; j++) bf[j] = *(const short8*)(brow + j * 16 * 32);
#pragma unroll
        for (int i = 0; i < 4; i++)
#pragma unroll
            for (int j = 0; j < 4; j++)
                acc[i][j] = __builtin_amdgcn_mfma_f32_16x16x32_bf16(
                    af[i], bf[j], acc[i][j], 0, 0, 0);
        __syncthreads();
    }

    // D layout: col = lane&15, row = quad*4 + r   [verified m89/m91]
    const int mw = m0 + wr * 64;
    const int nw = n0 + wc * 64;
    const int rb = quad * 4;
#pragma unroll
    for (int i = 0; i < 4; i++) {
#pragma unroll
        for (int j = 0; j < 4; j++) {
            const int n = nw + j * 16 + r16;
#pragma unroll
            for (int r = 0; r < 4; r++) {
                const int m = mw + i * 16 + rb + r;
                float v = acc[i][j][r];
                if (OUTM == 2) {
                    v += bias[n];
                    v = (v > 20.f) ? v : log1pf(__expf(v));
                }
                if (OUTM == 1)
                    ((float*)Cv)[(size_t)m * ldc + n] = v;
                else
                    ((u16*)Cv)[(size_t)m * ldc + n] = f2b(v);
                if (OUTM == 3 && n >= 64 && n < 96)
                    aux[(size_t)m * 32 + (n - 64)] = v;
            }
        }
    }
}

// =====================================================================
__global__ __launch_bounds__(256) void cvt_f2b(
    const float* __restrict__ in, u16* __restrict__ out, int n)
{
    int i = blockIdx.x * blockDim.x + threadIdx.x;
    if (i < n) out[i] = f2b(in[i]);
}

__global__ __launch_bounds__(256) void pad_wx(
    const float* __restrict__ W_x, u16* __restrict__ out)
{
    int idx = blockIdx.x * blockDim.x + threadIdx.x;   // over 128*2048
    int r = idx >> 11;
    int c = idx & 2047;
    out[idx] = (r < 96) ? f2b(W_x[r * 2048 + c]) : (u16)0;
}

// =====================================================================
// Depthwise causal conv (K=4) + SiLU.  Reads xr half of xz (stride 4096).
// =====================================================================
__global__ __launch_bounds__(256) void conv_silu(
    const u16* __restrict__ xz, const float* __restrict__ conv_w,
    const float* __restrict__ conv_b, u16* __restrict__ xs)
{
    int idx = blockIdx.x * blockDim.x + threadIdx.x;   // over M*DI
    int m = idx >> 11;
    int d = idx & 2047;
    int l = m & (Ll - 1);

    float acc = conv_b[d];
#pragma unroll
    for (int k = 0; k < KC; k++) {
        int li = l - (KC - 1) + k;
        if (li >= 0)
            acc += b2f(xz[(size_t)(m - (KC - 1) + k) * LDXZ + d]) * conv_w[d * KC + k];
    }
    float s = acc / (1.f + __expf(-acc));
    xs[(size_t)m * DI + d] = f2b(s);
}

// =====================================================================
// Chunked selective scan.  One THREAD per (channel, chunk); 16 states in
// registers; coalesced dt/xs/z; B/C broadcast fp32 from bcf sideband.
// Fast path (A_log = log(1..16), checked wave-uniformly): one exp +
// 15-mul power tree per step.  p1 tracks sum(dt) -> P at chunk end.
// dt lives in the xr half of xz (stride 4096); z in the other half.
// =====================================================================
__global__ __launch_bounds__(256) void scan_p1(
    const u16* __restrict__ xzdt, const u16* __restrict__ xs,
    const float* __restrict__ bcf, const float* __restrict__ A_log,
    float* __restrict__ scr_P, float* __restrict__ scr_hend)
{
    const int d = blockIdx.x * 256 + threadIdx.x;
    const int b = blockIdx.y;
    const int c = blockIdx.z;

    const float ad0 = -__expf(A_log[0]);
    float adl[DS];
    bool fast = true;
#pragma unroll
    for (int s = 0; s < DS; s++) {
        float av = -__expf(A_log[s]);
        adl[s] = av;
        float kr = (float)(s + 1);
        if (fabsf(av / ad0 - kr) > 1e-4f * kr) fast = false;
    }

    const int m0 = b * Ll + c * LC;
    const u16* dt_p = xzdt + (size_t)m0 * LDXZ + d;
    const u16* xs_p = xs + (size_t)m0 * DI + d;
    const float* bc_p = bcf + (size_t)m0 * 32;

    float h[DS] = {};
    float P[DS];
#pragma unroll
    for (int s = 0; s < DS; s++) P[s] = 1.f;
    float sdt = 0.f;

    // prefetch step 0
    u16 dt_c = dt_p[0];
    u16 xs_c = xs_p[0];
    floatx4 B0c = *(const floatx4*)(bc_p);
    floatx4 B1c = *(const floatx4*)(bc_p + 4);
    floatx4 B2c = *(const floatx4*)(bc_p + 8);
    floatx4 B3c = *(const floatx4*)(bc_p + 12);

    if (fast) {
        for (int l = 0; l < LC; l++) {
            // prefetch next (one benign in-workspace over-read at l=LC-1)
            u16 dt_n = dt_p[LDXZ];
            u16 xs_n = xs_p[DI];
            floatx4 B0n = *(const floatx4*)(bc_p + 32);
            floatx4 B1n = *(const floatx4*)(bc_p + 36);
            floatx4 B2n = *(const floatx4*)(bc_p + 40);
            floatx4 B3n = *(const floatx4*)(bc_p + 44);

            float dtv = b2f(dt_c);
            float xv  = b2f(xs_c);
            float bx = dtv * xv;
            sdt += dtv;
            float aa[DS];
            pow_tree(__expf(dtv * ad0), aa);
#pragma unroll
            for (int s = 0; s < DS; s++) {
                float Bv = (s < 4) ? B0c[s] : (s < 8) ? B1c[s - 4]
                         : (s < 12) ? B2c[s - 8] : B3c[s - 12];
                h[s] = aa[s] * h[s] + bx * Bv;
            }
            dt_c = dt_n; xs_c = xs_n;
            B0c = B0n; B1c = B1n; B2c = B2n; B3c = B3n;
            dt_p += LDXZ; xs_p += DI; bc_p += 32;
        }
        pow_tree(__expf(ad0 * sdt), P);
    } else {
        for (int l = 0; l < LC; l++) {
            u16 dt_n = dt_p[LDXZ];
            u16 xs_n = xs_p[DI];
            floatx4 B0n = *(const floatx4*)(bc_p + 32);
            floatx4 B1n = *(const floatx4*)(bc_p + 36);
            floatx4 B2n = *(const floatx4*)(bc_p + 40);
            floatx4 B3n = *(const floatx4*)(bc_p + 44);

            float dtv = b2f(dt_c);
            float xv  = b2f(xs_c);
            float bx = dtv * xv;
#pragma unroll
            for (int s = 0; s < DS; s++) {
                float Bv = (s < 4) ? B0c[s] : (s < 8) ? B1c[s - 4]
                         : (s < 12) ? B2c[s - 8] : B3c[s - 12];
                float a = __expf(dtv * adl[s]);
                h[s] = a * h[s] + bx * Bv;
                P[s] *= a;
            }
            dt_c = dt_n; xs_c = xs_n;
            B0c = B0n; B1c = B1n; B2c = B2n; B3c = B3n;
            dt_p += LDXZ; xs_p += DI; bc_p += 32;
        }
    }

    const size_t base = ((size_t)(b * NCHUNK + c) * DI + d) * DS;
#pragma unroll
    for (int s = 0; s < DS; s += 4) {
        floatx4 pv = {P[s], P[s+1], P[s+2], P[s+3]};
        floatx4 hv = {h[s], h[s+1], h[s+2], h[s+3]};
        *(floatx4*)(scr_P + base + s)    = pv;
        *(floatx4*)(scr_hend + base + s) = hv;
    }
}

__global__ __launch_bounds__(256) void scan_p2(
    float* __restrict__ scr_P, const float* __restrict__ scr_hend)
{
    const int t = blockIdx.x * 256 + threadIdx.x;   // (b, d, s)
    const int s = t & 15;
    const int d = (t >> 4) & (DI - 1);
    const int b = t >> 15;

    float hin = 0.f;
    for (int c = 0; c < NCHUNK; c++) {
        const size_t base = ((size_t)(b * NCHUNK + c) * DI + d) * DS + s;
        float p = scr_P[base];
        float he = scr_hend[base];
        scr_P[base] = hin;
        hin = p * hin + he;
    }
}

__global__ __launch_bounds__(256) void scan_p3(
    const u16* __restrict__ xz, const u16* xs, const float* __restrict__ bcf,
    const float* __restrict__ scr_hin, const float* __restrict__ A_log,
    const float* __restrict__ Dvec, u16* yg)
{
    const int d = blockIdx.x * 256 + threadIdx.x;
    const int b = blockIdx.y;
    const int c = blockIdx.z;

    const float ad0 = -__expf(A_log[0]);
    float adl[DS];
    bool fast = true;
#pragma unroll
    for (int s = 0; s < DS; s++) {
        float av = -__expf(A_log[s]);
        adl[s] = av;
        float kr = (float)(s + 1);
        if (fabsf(av / ad0 - kr) > 1e-4f * kr) fast = false;
    }
    const float Dd = Dvec[d];

    const int m0 = b * Ll + c * LC;
    const u16* dt_p = xz + (size_t)m0 * LDXZ + d;          // xr half = dt
    const u16* z_p  = xz + (size_t)m0 * LDXZ + 2048 + d;   // z half
    const u16* xs_p = xs + (size_t)m0 * DI + d;
    const float* bc_p = bcf + (size_t)m0 * 32;
    u16* yg_p = yg + (size_t)m0 * DI + d;

    float h[DS];
    const size_t base = ((size_t)(b * NCHUNK + c) * DI + d) * DS;
#pragma unroll
    for (int s = 0; s < DS; s += 4) {
        floatx4 hv = *(const floatx4*)(scr_hin + base + s);
        h[s] = hv[0]; h[s+1] = hv[1]; h[s+2] = hv[2]; h[s+3] = hv[3];
    }

    // prefetch step 0
    u16 dt_c = dt_p[0];
    u16 xs_c = xs_p[0];
    u16 z_c  = z_p[0];
    floatx4 Bc[4], Cc[4];
#pragma unroll
    for (int q = 0; q < 4; q++) {
        Bc[q] = *(const floatx4*)(bc_p + q * 4);
        Cc[q] = *(const floatx4*)(bc_p + 16 + q * 4);
    }

    for (int l = 0; l < LC; l++) {
        u16 dt_n = dt_p[LDXZ];
        u16 xs_n = xs_p[DI];
        u16 z_n  = z_p[LDXZ];
        floatx4 Bn[4], Cn[4];
#pragma unroll
        for (int q = 0; q < 4; q++) {
            Bn[q] = *(const floatx4*)(bc_p + 32 + q * 4);
            Cn[q] = *(const floatx4*)(bc_p + 48 + q * 4);
        }

        float dtv = b2f(dt_c);
        float xv  = b2f(xs_c);
        float bx = dtv * xv;
        float aa[DS];
        if (fast) {
            pow_tree(__expf(dtv * ad0), aa);
        } else {
#pragma unroll
            for (int s = 0; s < DS; s++) aa[s] = __expf(dtv * adl[s]);
        }
        float y0 = 0.f, y1 = 0.f, y2 = 0.f, y3 = 0.f;
#pragma unroll
        for (int q = 0; q < 4; q++) {
#pragma unroll
            for (int j = 0; j < 4; j++) {
                int s = q * 4 + j;
                h[s] = aa[s] * h[s] + bx * Bc[q][j];
            }
        }
#pragma unroll
        for (int j = 0; j < 4; j++) {
            y0 += h[j] * Cc[0][j];
            y1 += h[4 + j] * Cc[1][j];
            y2 += h[8 + j] * Cc[2][j];
            y3 += h[12 + j] * Cc[3][j];
        }
        float yt = ((y0 + y1) + (y2 + y3)) + Dd * xv;
        float zv = b2f(z_c);
        float g = zv / (1.f + __expf(-zv));
        yg_p[0] = f2b(yt * g);

        dt_c = dt_n; xs_c = xs_n; z_c = z_n;
#pragma unroll
        for (int q = 0; q < 4; q++) { Bc[q] = Bn[q]; Cc[q] = Cn[q]; }
        dt_p += LDXZ; xs_p += DI; z_p += LDXZ; bc_p += 32; yg_p += DI;
    }
}

// =====================================================================
extern "C" void kernel_launch(void* const* d_in, const int* in_sizes, int n_in,
                              void* d_out, int out_size, void* d_ws, size_t ws_size,
                              hipStream_t stream)
{
    const float* x      = (const float*)d_in[0];   // (B,L,DM)
    const float* W_in   = (const float*)d_in[1];   // (2*DI, DM)
    const float* conv_w = (const float*)d_in[2];   // (DI, KC)
    const float* conv_b = (const float*)d_in[3];   // (DI,)
    const float* A_log  = (const float*)d_in[4];   // (DS,)
    const float* Dvec   = (const float*)d_in[5];   // (DI,)
    const float* W_x    = (const float*)d_in[6];   // (96, DI)
    const float* W_dt   = (const float*)d_in[7];   // (DI, DTR)
    const float* b_dt   = (const float*)d_in[8];   // (DI,)
    const float* W_out  = (const float*)d_in[9];   // (DM, DI)

    // ---- workspace arena (bf16 u16 elements), ~133 MB total ----
    u16* ws = (u16*)d_ws;
    u16* xz    = ws;                 ws += (size_t)M * LDXZ;     // 67.1 MB (xr|z interleaved; xr half reused for dt)
    u16* xs    = ws;                 ws += (size_t)M * DI;       // 33.55 MB (yg in-place)
    u16* xbf   = ws;                 ws += (size_t)M * DM;       // 16.78 MB (reused as scan scratch)
    u16* wibf  = ws;                 ws += (size_t)2 * DI * DM;  // 8.39 MB (reused as bcf)
    u16* wxp   = ws;                 ws += (size_t)NPAD * DI;    // 0.52 MB
    u16* wdtb  = ws;                 ws += (size_t)DI * DTR;     // 0.26 MB
    u16* woutb = ws;                 ws += (size_t)DM * DI;      // 4.19 MB
    u16* xdbl  = ws;                 ws += (size_t)M * NPAD;     // 2.10 MB
    u16* yg    = xs;                 // in-place
    float* scr_P    = (float*)xbf;   // 8.39 MB (xbf dead after GEMM1)
    float* scr_hend = scr_P + (size_t)Bb * NCHUNK * DI * DS;   // 8.39 MB
    float* bcf      = (float*)wibf;  // 1.05 MB (wibf dead after GEMM1)

    // 0) conversions for GEMM operands
    cvt_f2b<<<(M * DM) / 256, 256, 0, stream>>>(x, xbf, M * DM);
    cvt_f2b<<<(2 * DI * DM) / 256, 256, 0, stream>>>(W_in, wibf, 2 * DI * DM);
    pad_wx<<<(NPAD * DI) / 256, 256, 0, stream>>>(W_x, wxp);
    cvt_f2b<<<(DI * DTR) / 256, 256, 0, stream>>>(W_dt, wdtb, DI * DTR);
    cvt_f2b<<<(DM * DI) / 256, 256, 0, stream>>>(W_out, woutb, DM * DI);

    // 1) xz = x @ W_in^T   (8192 x 4096, K=1024) — merged xr|z
    gemm_bt<0><<<dim3(LDXZ / 128, M / 128), 256, 0, stream>>>(
        xbf, wibf, xz, nullptr, nullptr, DM, DM, DM, LDXZ);

    // 2) conv + silu -> xs   (reads xr half of xz)
    conv_silu<<<(M * DI) / 256, 256, 0, stream>>>(xz, conv_w, conv_b, xs);

    // 3) x_dbl = xs @ wxp^T (8192 x 128, K=2048) + fp32 B/C sideband -> bcf
    gemm_bt<3><<<dim3(NPAD / 128, M / 128), 256, 0, stream>>>(
        xs, wxp, xdbl, nullptr, bcf, DI, DI, DI, NPAD);

    // 4) dt = softplus(x_dbl[:, :64] @ W_dt^T + b_dt) -> xr half of xz
    //    (conv already consumed xr; z half untouched, ldc=4096)
    gemm_bt<2><<<dim3(DI / 128, M / 128), 256, 0, stream>>>(
        xdbl, wdtb, xz, b_dt, nullptr, DTR, NPAD, DTR, LDXZ);

    // 5) chunked scan
    scan_p1<<<dim3(DI / 256, Bb, NCHUNK), 256, 0, stream>>>(
        xz, xs, bcf, A_log, scr_P, scr_hend);
    scan_p2<<<(Bb * DI * DS) / 256, 256, 0, stream>>>(scr_P, scr_hend);
    scan_p3<<<dim3(DI / 256, Bb, NCHUNK), 256, 0, stream>>>(
        xz, xs, bcf, scr_P, A_log, Dvec, yg);

    // 6) out = yg @ W_out^T   (8192 x 1024, K=2048), fp32 store
    gemm_bt<1><<<dim3(DM / 128, M / 128), 256, 0, stream>>>(
        yg, woutb, d_out, nullptr, nullptr, DI, DI, DI, DM);
}

// Round 7
// 517.473 us; speedup vs baseline: 1.3003x; 1.1202x over previous
//
#include <hip/hip_runtime.h>
#include <math.h>

typedef unsigned short u16;
typedef unsigned int u32;

// ---- problem constants ----
constexpr int Bb = 4, Ll = 2048, DM = 1024, DI = 2048, DS = 16, DTR = 64, KC = 4;
constexpr int M = Bb * Ll;            // 8192 rows
constexpr int NPAD = 128;             // padded x_dbl width (64 + 2*16 = 96 -> 128)
constexpr int NCHUNK = 16;            // scan chunks
constexpr int LC = Ll / NCHUNK;       // 128 steps per chunk
constexpr int LDXZ = 4096;            // xz row stride (xr|z interleaved)

// ---- bf16 helpers on raw u16 ----
__device__ __forceinline__ float b2f(u16 u) {
    return __uint_as_float(((u32)u) << 16);
}
__device__ __forceinline__ u16 f2b(float f) {
    u32 x = __float_as_uint(f);
    u32 r = (x + 0x7fffu + ((x >> 16) & 1u)) >> 16;   // round-to-nearest-even
    return (u16)r;
}

typedef __attribute__((ext_vector_type(8))) short short8;
typedef __attribute__((ext_vector_type(4))) short short4v;
typedef __attribute__((ext_vector_type(4))) float floatx4;

// async global->LDS, 16B per lane; LDS dest = wave-uniform base + lane*16
__device__ __forceinline__ void gload16(const u16* g, u16* l) {
    __builtin_amdgcn_global_load_lds(
        (const __attribute__((address_space(1))) void*)g,
        (__attribute__((address_space(3))) void*)l,
        16, 0, 0);
}

// a^(s+1) for s=0..15 from base a, tree form (15 muls, depth 4)
__device__ __forceinline__ void pow_tree(float a, float* aa) {
    float a2 = a * a, a4 = a2 * a2, a8 = a4 * a4;
    aa[0] = a;        aa[1] = a2;       aa[2] = a * a2;   aa[3] = a4;
    aa[4] = a * a4;   aa[5] = a2 * a4;  aa[6] = aa[2] * a4; aa[7] = a8;
    aa[8] = a * a8;   aa[9] = a2 * a8;  aa[10] = aa[2] * a8; aa[11] = a4 * a8;
    aa[12] = aa[4] * a8; aa[13] = aa[5] * a8; aa[14] = aa[6] * a8; aa[15] = a8 * a8;
}

// =====================================================================
// C(MxN) = A(MxK) * B(NxK)^T, bf16 in, fp32 MFMA acc.  m97 structure
// + k-chunk rotation swizzle: LDS slot (row,s) holds global k-chunk
// (s + ((row&15)>>1)) & 3, so each ds_read_b128 phase lands 2/bank (free).
// OUTM: 0 = bf16 store, 1 = fp32 store, 2 = softplus(acc + bias[n]) bf16,
//       3 = bf16 store + fp32 sideband of cols [64,96) into aux (ld 32),
//       4 = split-K partial: fp32 store to aux-style part buffer,
//           k-slice = blockIdx.z (K passed = per-slice K)
// =====================================================================
template<int OUTM>
__global__ __launch_bounds__(256) void gemm_bt(
    const u16* __restrict__ A, const u16* __restrict__ Bm,
    void* __restrict__ Cv, const float* __restrict__ bias,
    float* __restrict__ aux,
    int K, int lda, int ldb, int ldc)
{
    __shared__ alignas(16) u16 ldsA[128 * 32];
    __shared__ alignas(16) u16 ldsB[128 * 32];

    const int lane = threadIdx.x & 63;
    const int wave = threadIdx.x >> 6;
    const int wr = wave >> 1, wc = wave & 1;
    const int m0 = blockIdx.y * 128;
    const int n0 = blockIdx.x * 128;
    const int koff = (OUTM == 4) ? blockIdx.z * K : 0;

    // staging: lane covers LDS row (lane>>2), slot (lane&3); source k-chunk
    // swizzled by rot(row) = (lane>>3)&3
    const int srow = wave * 32 + (lane >> 2);
    const int skc  = (((lane & 3) + (lane >> 3)) & 3) * 8;
    const u16* Ag = A + (size_t)(m0 + srow) * lda + skc + koff;
    const u16* Bg = Bm + (size_t)(n0 + srow) * ldb + skc + koff;
    u16* lA = &ldsA[wave * 1024];
    u16* lB = &ldsB[wave * 1024];

    const int r16 = lane & 15;
    const int quad = lane >> 4;
    // reader: global k-chunk `quad` lives in slot (quad - rot(r16)) & 3
    const int slot = (quad + 4 - ((r16 >> 1) & 3)) & 3;
    const u16* arow = &ldsA[(wr * 64 + r16) * 32 + slot * 8];
    const u16* brow = &ldsB[(wc * 64 + r16) * 32 + slot * 8];

    floatx4 acc[4][4] = {};

    for (int k0 = 0; k0 < K; k0 += 32) {
        gload16(Ag + k0,                    lA);
        gload16(Ag + k0 + (size_t)16 * lda, lA + 512);
        gload16(Bg + k0,                    lB);
        gload16(Bg + k0 + (size_t)16 * ldb, lB + 512);
        __syncthreads();

        short8 af[4], bf[4];
#pragma unroll
        for (int i = 0; i < 4; i++) af[i] = *(const short8*)(arow + i * 16 * 32);
#pragma unroll
        for (int j = 0; j < 4; j++) bf[j] = *(const short8*)(brow + j * 16 * 32);
#pragma unroll
        for (int i = 0; i < 4; i++)
#pragma unroll
            for (int j = 0; j < 4; j++)
                acc[i][j] = __builtin_amdgcn_mfma_f32_16x16x32_bf16(
                    af[i], bf[j], acc[i][j], 0, 0, 0);
        __syncthreads();
    }

    // D layout: col = lane&15, row = quad*4 + r   [verified m89/m91]
    const int mw = m0 + wr * 64;
    const int nw = n0 + wc * 64;
    const int rb = quad * 4;
#pragma unroll
    for (int i = 0; i < 4; i++) {
#pragma unroll
        for (int j = 0; j < 4; j++) {
            const int n = nw + j * 16 + r16;
#pragma unroll
            for (int r = 0; r < 4; r++) {
                const int m = mw + i * 16 + rb + r;
                float v = acc[i][j][r];
                if (OUTM == 2) {
                    v += bias[n];
                    v = (v > 20.f) ? v : log1pf(__expf(v));
                }
                if (OUTM == 4)
                    ((float*)Cv)[((size_t)blockIdx.z * M + m) * ldc + n] = v;
                else if (OUTM == 1)
                    ((float*)Cv)[(size_t)m * ldc + n] = v;
                else
                    ((u16*)Cv)[(size_t)m * ldc + n] = f2b(v);
                if (OUTM == 3 && n >= 64 && n < 96)
                    aux[(size_t)m * 32 + (n - 64)] = v;
            }
        }
    }
}

// =====================================================================
// reduce 4 split-K fp32 partials -> bf16 xdbl + fp32 bcf sideband
// =====================================================================
__global__ __launch_bounds__(256) void redk_gemm3(
    const float* __restrict__ part, u16* __restrict__ xdbl,
    float* __restrict__ bcf)
{
    const int t = blockIdx.x * 256 + threadIdx.x;   // over M*32
    const int n4 = (t & 31) * 4;
    const int m = t >> 5;
    const size_t stride = (size_t)M * NPAD;
    const float* p = part + (size_t)m * NPAD + n4;
    floatx4 acc = *(const floatx4*)(p)
                + *(const floatx4*)(p + stride)
                + *(const floatx4*)(p + 2 * stride)
                + *(const floatx4*)(p + 3 * stride);
    short4v ob;
#pragma unroll
    for (int j = 0; j < 4; j++) ob[j] = (short)f2b(acc[j]);
    *(short4v*)(xdbl + (size_t)m * NPAD + n4) = ob;
    if (n4 >= 64 && n4 < 96)
        *(floatx4*)(bcf + (size_t)m * 32 + (n4 - 64)) = acc;
}

// =====================================================================
__global__ __launch_bounds__(256) void cvt_f2b(
    const float* __restrict__ in, u16* __restrict__ out, int n)
{
    int i = blockIdx.x * blockDim.x + threadIdx.x;
    if (i < n) out[i] = f2b(in[i]);
}

__global__ __launch_bounds__(256) void pad_wx(
    const float* __restrict__ W_x, u16* __restrict__ out)
{
    int idx = blockIdx.x * blockDim.x + threadIdx.x;   // over 128*2048
    int r = idx >> 11;
    int c = idx & 2047;
    out[idx] = (r < 96) ? f2b(W_x[r * 2048 + c]) : (u16)0;
}

// =====================================================================
// Depthwise causal conv (K=4) + SiLU, vectorized: one block per row m,
// 8 channels per thread, short8 loads/stores; causal branch wave-uniform.
// =====================================================================
__global__ __launch_bounds__(256) void conv_silu(
    const u16* __restrict__ xz, const float* __restrict__ conv_w,
    const float* __restrict__ conv_b, u16* __restrict__ xs)
{
    const int m = blockIdx.x;
    const int d0 = threadIdx.x * 8;
    const int l = m & (Ll - 1);

    float acc[8];
    {
        floatx4 cb0 = *(const floatx4*)(conv_b + d0);
        floatx4 cb1 = *(const floatx4*)(conv_b + d0 + 4);
#pragma unroll
        for (int j = 0; j < 4; j++) { acc[j] = cb0[j]; acc[4 + j] = cb1[j]; }
    }
    float w[8][KC];
#pragma unroll
    for (int jd = 0; jd < 8; jd++) {
        floatx4 wv = *(const floatx4*)(conv_w + (d0 + jd) * KC);
#pragma unroll
        for (int k = 0; k < KC; k++) w[jd][k] = wv[k];
    }
#pragma unroll
    for (int k = 0; k < KC; k++) {
        int li = l - (KC - 1) + k;
        if (li >= 0) {
            short8 xv = *(const short8*)(xz + (size_t)(m - (KC - 1) + k) * LDXZ + d0);
#pragma unroll
            for (int jd = 0; jd < 8; jd++)
                acc[jd] += b2f((u16)xv[jd]) * w[jd][k];
        }
    }
    short8 o;
#pragma unroll
    for (int jd = 0; jd < 8; jd++) {
        float s = acc[jd] / (1.f + __expf(-acc[jd]));
        o[jd] = (short)f2b(s);
    }
    *(short8*)(xs + (size_t)m * DI + d0) = o;
}

// =====================================================================
// Chunked selective scan.  One THREAD per (channel, chunk); 16 states in
// registers; coalesced dt/xs/z; B/C broadcast fp32 from bcf sideband.
// Fast path (A_log = log(1..16), checked wave-uniformly): one exp +
// 15-mul power tree per step.  p1 tracks sum(dt) -> P at chunk end.
// dt lives in the xr half of xz (stride 4096); z in the other half.
// =====================================================================
__global__ __launch_bounds__(256) void scan_p1(
    const u16* __restrict__ xzdt, const u16* __restrict__ xs,
    const float* __restrict__ bcf, const float* __restrict__ A_log,
    float* __restrict__ scr_P, float* __restrict__ scr_hend)
{
    const int d = blockIdx.x * 256 + threadIdx.x;
    const int b = blockIdx.y;
    const int c = blockIdx.z;

    const float ad0 = -__expf(A_log[0]);
    float adl[DS];
    bool fast = true;
#pragma unroll
    for (int s = 0; s < DS; s++) {
        float av = -__expf(A_log[s]);
        adl[s] = av;
        float kr = (float)(s + 1);
        if (fabsf(av / ad0 - kr) > 1e-4f * kr) fast = false;
    }

    const int m0 = b * Ll + c * LC;
    const u16* dt_p = xzdt + (size_t)m0 * LDXZ + d;
    const u16* xs_p = xs + (size_t)m0 * DI + d;
    const float* bc_p = bcf + (size_t)m0 * 32;

    float h[DS] = {};
    float P[DS];
#pragma unroll
    for (int s = 0; s < DS; s++) P[s] = 1.f;
    float sdt = 0.f;

    u16 dt_c = dt_p[0];
    u16 xs_c = xs_p[0];
    floatx4 B0c = *(const floatx4*)(bc_p);
    floatx4 B1c = *(const floatx4*)(bc_p + 4);
    floatx4 B2c = *(const floatx4*)(bc_p + 8);
    floatx4 B3c = *(const floatx4*)(bc_p + 12);

    if (fast) {
        for (int l = 0; l < LC; l++) {
            u16 dt_n = dt_p[LDXZ];
            u16 xs_n = xs_p[DI];
            floatx4 B0n = *(const floatx4*)(bc_p + 32);
            floatx4 B1n = *(const floatx4*)(bc_p + 36);
            floatx4 B2n = *(const floatx4*)(bc_p + 40);
            floatx4 B3n = *(const floatx4*)(bc_p + 44);

            float dtv = b2f(dt_c);
            float xv  = b2f(xs_c);
            float bx = dtv * xv;
            sdt += dtv;
            float aa[DS];
            pow_tree(__expf(dtv * ad0), aa);
#pragma unroll
            for (int s = 0; s < DS; s++) {
                float Bv = (s < 4) ? B0c[s] : (s < 8) ? B1c[s - 4]
                         : (s < 12) ? B2c[s - 8] : B3c[s - 12];
                h[s] = aa[s] * h[s] + bx * Bv;
            }
            dt_c = dt_n; xs_c = xs_n;
            B0c = B0n; B1c = B1n; B2c = B2n; B3c = B3n;
            dt_p += LDXZ; xs_p += DI; bc_p += 32;
        }
        pow_tree(__expf(ad0 * sdt), P);
    } else {
        for (int l = 0; l < LC; l++) {
            u16 dt_n = dt_p[LDXZ];
            u16 xs_n = xs_p[DI];
            floatx4 B0n = *(const floatx4*)(bc_p + 32);
            floatx4 B1n = *(const floatx4*)(bc_p + 36);
            floatx4 B2n = *(const floatx4*)(bc_p + 40);
            floatx4 B3n = *(const floatx4*)(bc_p + 44);

            float dtv = b2f(dt_c);
            float xv  = b2f(xs_c);
            float bx = dtv * xv;
#pragma unroll
            for (int s = 0; s < DS; s++) {
                float Bv = (s < 4) ? B0c[s] : (s < 8) ? B1c[s - 4]
                         : (s < 12) ? B2c[s - 8] : B3c[s - 12];
                float a = __expf(dtv * adl[s]);
                h[s] = a * h[s] + bx * Bv;
                P[s] *= a;
            }
            dt_c = dt_n; xs_c = xs_n;
            B0c = B0n; B1c = B1n; B2c = B2n; B3c = B3n;
            dt_p += LDXZ; xs_p += DI; bc_p += 32;
        }
    }

    const size_t base = ((size_t)(b * NCHUNK + c) * DI + d) * DS;
#pragma unroll
    for (int s = 0; s < DS; s += 4) {
        floatx4 pv = {P[s], P[s+1], P[s+2], P[s+3]};
        floatx4 hv = {h[s], h[s+1], h[s+2], h[s+3]};
        *(floatx4*)(scr_P + base + s)    = pv;
        *(floatx4*)(scr_hend + base + s) = hv;
    }
}

__global__ __launch_bounds__(256) void scan_p2(
    float* __restrict__ scr_P, const float* __restrict__ scr_hend)
{
    const int t = blockIdx.x * 256 + threadIdx.x;   // (b, d, s)
    const int s = t & 15;
    const int d = (t >> 4) & (DI - 1);
    const int b = t >> 15;

    float hin = 0.f;
    for (int c = 0; c < NCHUNK; c++) {
        const size_t base = ((size_t)(b * NCHUNK + c) * DI + d) * DS + s;
        float p = scr_P[base];
        float he = scr_hend[base];
        scr_P[base] = hin;
        hin = p * hin + he;
    }
}

__global__ __launch_bounds__(256) void scan_p3(
    const u16* __restrict__ xz, const u16* xs, const float* __restrict__ bcf,
    const float* __restrict__ scr_hin, const float* __restrict__ A_log,
    const float* __restrict__ Dvec, u16* yg)
{
    const int d = blockIdx.x * 256 + threadIdx.x;
    const int b = blockIdx.y;
    const int c = blockIdx.z;

    const float ad0 = -__expf(A_log[0]);
    float adl[DS];
    bool fast = true;
#pragma unroll
    for (int s = 0; s < DS; s++) {
        float av = -__expf(A_log[s]);
        adl[s] = av;
        float kr = (float)(s + 1);
        if (fabsf(av / ad0 - kr) > 1e-4f * kr) fast = false;
    }
    const float Dd = Dvec[d];

    const int m0 = b * Ll + c * LC;
    const u16* dt_p = xz + (size_t)m0 * LDXZ + d;          // xr half = dt
    const u16* z_p  = xz + (size_t)m0 * LDXZ + 2048 + d;   // z half
    const u16* xs_p = xs + (size_t)m0 * DI + d;
    const float* bc_p = bcf + (size_t)m0 * 32;
    u16* yg_p = yg + (size_t)m0 * DI + d;

    float h[DS];
    const size_t base = ((size_t)(b * NCHUNK + c) * DI + d) * DS;
#pragma unroll
    for (int s = 0; s < DS; s += 4) {
        floatx4 hv = *(const floatx4*)(scr_hin + base + s);
        h[s] = hv[0]; h[s+1] = hv[1]; h[s+2] = hv[2]; h[s+3] = hv[3];
    }

    u16 dt_c = dt_p[0];
    u16 xs_c = xs_p[0];
    u16 z_c  = z_p[0];
    floatx4 Bc[4], Cc[4];
#pragma unroll
    for (int q = 0; q < 4; q++) {
        Bc[q] = *(const floatx4*)(bc_p + q * 4);
        Cc[q] = *(const floatx4*)(bc_p + 16 + q * 4);
    }

    for (int l = 0; l < LC; l++) {
        u16 dt_n = dt_p[LDXZ];
        u16 xs_n = xs_p[DI];
        u16 z_n  = z_p[LDXZ];
        floatx4 Bn[4], Cn[4];
#pragma unroll
        for (int q = 0; q < 4; q++) {
            Bn[q] = *(const floatx4*)(bc_p + 32 + q * 4);
            Cn[q] = *(const floatx4*)(bc_p + 48 + q * 4);
        }

        float dtv = b2f(dt_c);
        float xv  = b2f(xs_c);
        float bx = dtv * xv;
        float aa[DS];
        if (fast) {
            pow_tree(__expf(dtv * ad0), aa);
        } else {
#pragma unroll
            for (int s = 0; s < DS; s++) aa[s] = __expf(dtv * adl[s]);
        }
        float y0 = 0.f, y1 = 0.f, y2 = 0.f, y3 = 0.f;
#pragma unroll
        for (int q = 0; q < 4; q++) {
#pragma unroll
            for (int j = 0; j < 4; j++) {
                int s = q * 4 + j;
                h[s] = aa[s] * h[s] + bx * Bc[q][j];
            }
        }
#pragma unroll
        for (int j = 0; j < 4; j++) {
            y0 += h[j] * Cc[0][j];
            y1 += h[4 + j] * Cc[1][j];
            y2 += h[8 + j] * Cc[2][j];
            y3 += h[12 + j] * Cc[3][j];
        }
        float yt = ((y0 + y1) + (y2 + y3)) + Dd * xv;
        float zv = b2f(z_c);
        float g = zv / (1.f + __expf(-zv));
        yg_p[0] = f2b(yt * g);

        dt_c = dt_n; xs_c = xs_n; z_c = z_n;
#pragma unroll
        for (int q = 0; q < 4; q++) { Bc[q] = Bn[q]; Cc[q] = Cn[q]; }
        dt_p += LDXZ; xs_p += DI; z_p += LDXZ; bc_p += 32; yg_p += DI;
    }
}

// =====================================================================
extern "C" void kernel_launch(void* const* d_in, const int* in_sizes, int n_in,
                              void* d_out, int out_size, void* d_ws, size_t ws_size,
                              hipStream_t stream)
{
    const float* x      = (const float*)d_in[0];   // (B,L,DM)
    const float* W_in   = (const float*)d_in[1];   // (2*DI, DM)
    const float* conv_w = (const float*)d_in[2];   // (DI, KC)
    const float* conv_b = (const float*)d_in[3];   // (DI,)
    const float* A_log  = (const float*)d_in[4];   // (DS,)
    const float* Dvec   = (const float*)d_in[5];   // (DI,)
    const float* W_x    = (const float*)d_in[6];   // (96, DI)
    const float* W_dt   = (const float*)d_in[7];   // (DI, DTR)
    const float* b_dt   = (const float*)d_in[8];   // (DI,)
    const float* W_out  = (const float*)d_in[9];   // (DM, DI)

    // ---- workspace arena (bf16 u16 elements), ~133 MB total ----
    u16* ws = (u16*)d_ws;
    u16* xz    = ws;                 ws += (size_t)M * LDXZ;     // 67.1 MB (xr|z; xr half reused for dt)
    u16* xs    = ws;                 ws += (size_t)M * DI;       // 33.55 MB (yg in-place)
    u16* xbf   = ws;                 ws += (size_t)M * DM;       // 16.78 MB (x bf16 -> split-K parts -> scan scratch)
    u16* wibf  = ws;                 ws += (size_t)2 * DI * DM;  // 8.39 MB (reused as bcf)
    u16* wxp   = ws;                 ws += (size_t)NPAD * DI;    // 0.52 MB
    u16* wdtb  = ws;                 ws += (size_t)DI * DTR;     // 0.26 MB
    u16* woutb = ws;                 ws += (size_t)DM * DI;      // 4.19 MB
    u16* xdbl  = ws;                 ws += (size_t)M * NPAD;     // 2.10 MB
    u16* yg    = xs;                 // in-place
    float* part     = (float*)xbf;   // split-K partials (16.78 MB, xbf dead after GEMM1)
    float* scr_P    = (float*)xbf;   // scan scratch (after reduce consumed parts)
    float* scr_hend = scr_P + (size_t)Bb * NCHUNK * DI * DS;
    float* bcf      = (float*)wibf;  // 1.05 MB (wibf dead after GEMM1)

    // 0) conversions for GEMM operands
    cvt_f2b<<<(M * DM) / 256, 256, 0, stream>>>(x, xbf, M * DM);
    cvt_f2b<<<(2 * DI * DM) / 256, 256, 0, stream>>>(W_in, wibf, 2 * DI * DM);
    pad_wx<<<(NPAD * DI) / 256, 256, 0, stream>>>(W_x, wxp);
    cvt_f2b<<<(DI * DTR) / 256, 256, 0, stream>>>(W_dt, wdtb, DI * DTR);
    cvt_f2b<<<(DM * DI) / 256, 256, 0, stream>>>(W_out, woutb, DM * DI);

    // 1) xz = x @ W_in^T   (8192 x 4096, K=1024) — merged xr|z
    gemm_bt<0><<<dim3(LDXZ / 128, M / 128), 256, 0, stream>>>(
        xbf, wibf, xz, nullptr, nullptr, DM, DM, DM, LDXZ);

    // 2) conv + silu -> xs   (reads xr half of xz)
    conv_silu<<<M, 256, 0, stream>>>(xz, conv_w, conv_b, xs);

    // 3) x_dbl = xs @ wxp^T, split-K x4 -> fp32 parts, then reduce
    gemm_bt<4><<<dim3(1, M / 128, 4), 256, 0, stream>>>(
        xs, wxp, part, nullptr, nullptr, DI / 4, DI, DI, NPAD);
    redk_gemm3<<<(M * 32) / 256, 256, 0, stream>>>(part, xdbl, bcf);

    // 4) dt = softplus(x_dbl[:, :64] @ W_dt^T + b_dt) -> xr half of xz
    gemm_bt<2><<<dim3(DI / 128, M / 128), 256, 0, stream>>>(
        xdbl, wdtb, xz, b_dt, nullptr, DTR, NPAD, DTR, LDXZ);

    // 5) chunked scan
    scan_p1<<<dim3(DI / 256, Bb, NCHUNK), 256, 0, stream>>>(
        xz, xs, bcf, A_log, scr_P, scr_hend);
    scan_p2<<<(Bb * DI * DS) / 256, 256, 0, stream>>>(scr_P, scr_hend);
    scan_p3<<<dim3(DI / 256, Bb, NCHUNK), 256, 0, stream>>>(
        xz, xs, bcf, scr_P, A_log, Dvec, yg);

    // 6) out = yg @ W_out^T   (8192 x 1024, K=2048), fp32 store
    gemm_bt<1><<<dim3(DM / 128, M / 128), 256, 0, stream>>>(
        yg, woutb, d_out, nullptr, nullptr, DI, DI, DI, DM);
}

// Round 8
// 515.653 us; speedup vs baseline: 1.3049x; 1.0035x over previous
//
#include <hip/hip_runtime.h>
#include <math.h>

typedef unsigned short u16;
typedef unsigned int u32;

// ---- problem constants ----
constexpr int Bb = 4, Ll = 2048, DM = 1024, DI = 2048, DS = 16, DTR = 64, KC = 4;
constexpr int M = Bb * Ll;            // 8192 rows
constexpr int NPAD = 128;             // padded x_dbl width (64 + 2*16 = 96 -> 128)
constexpr int NCHUNK = 16;            // scan chunks
constexpr int LC = Ll / NCHUNK;       // 128 steps per chunk
constexpr int LDXZ = 4096;            // xz row stride (xr|z interleaved)

// ---- bf16 helpers on raw u16 ----
__device__ __forceinline__ float b2f(u16 u) {
    return __uint_as_float(((u32)u) << 16);
}
__device__ __forceinline__ u16 f2b(float f) {
    u32 x = __float_as_uint(f);
    u32 r = (x + 0x7fffu + ((x >> 16) & 1u)) >> 16;   // round-to-nearest-even
    return (u16)r;
}

typedef __attribute__((ext_vector_type(8))) short short8;
typedef __attribute__((ext_vector_type(4))) short short4v;
typedef __attribute__((ext_vector_type(4))) float floatx4;

// async global->LDS, 16B per lane; LDS dest = wave-uniform base + lane*16
__device__ __forceinline__ void gload16(const u16* g, u16* l) {
    __builtin_amdgcn_global_load_lds(
        (const __attribute__((address_space(1))) void*)g,
        (__attribute__((address_space(3))) void*)l,
        16, 0, 0);
}

// a^(s+1) for s=0..15 from base a, tree form (15 muls, depth 4)
__device__ __forceinline__ void pow_tree(float a, float* aa) {
    float a2 = a * a, a4 = a2 * a2, a8 = a4 * a4;
    aa[0] = a;        aa[1] = a2;       aa[2] = a * a2;   aa[3] = a4;
    aa[4] = a * a4;   aa[5] = a2 * a4;  aa[6] = aa[2] * a4; aa[7] = a8;
    aa[8] = a * a8;   aa[9] = a2 * a8;  aa[10] = aa[2] * a8; aa[11] = a4 * a8;
    aa[12] = aa[4] * a8; aa[13] = aa[5] * a8; aa[14] = aa[6] * a8; aa[15] = a8 * a8;
}

// =====================================================================
// C(MxN) = A(MxK) * B(NxK)^T, bf16 in, fp32 MFMA acc.  m97 structure
// + k-chunk rotation swizzle (conflict-free ds_read_b128).
// OUTM: 0 = bf16 store, 1 = fp32 store, 2 = softplus(acc + bias[n]) bf16,
//       4 = split-K partial: fp32 store, k-slice = blockIdx.z
// =====================================================================
template<int OUTM>
__global__ __launch_bounds__(256) void gemm_bt(
    const u16* __restrict__ A, const u16* __restrict__ Bm,
    void* __restrict__ Cv, const float* __restrict__ bias,
    int K, int lda, int ldb, int ldc)
{
    __shared__ alignas(16) u16 ldsA[128 * 32];
    __shared__ alignas(16) u16 ldsB[128 * 32];

    const int lane = threadIdx.x & 63;
    const int wave = threadIdx.x >> 6;
    const int wr = wave >> 1, wc = wave & 1;
    const int m0 = blockIdx.y * 128;
    const int n0 = blockIdx.x * 128;
    const int koff = (OUTM == 4) ? blockIdx.z * K : 0;

    const int srow = wave * 32 + (lane >> 2);
    const int skc  = (((lane & 3) + (lane >> 3)) & 3) * 8;
    const u16* Ag = A + (size_t)(m0 + srow) * lda + skc + koff;
    const u16* Bg = Bm + (size_t)(n0 + srow) * ldb + skc + koff;
    u16* lA = &ldsA[wave * 1024];
    u16* lB = &ldsB[wave * 1024];

    const int r16 = lane & 15;
    const int quad = lane >> 4;
    const int slot = (quad + 4 - ((r16 >> 1) & 3)) & 3;
    const u16* arow = &ldsA[(wr * 64 + r16) * 32 + slot * 8];
    const u16* brow = &ldsB[(wc * 64 + r16) * 32 + slot * 8];

    floatx4 acc[4][4] = {};

    for (int k0 = 0; k0 < K; k0 += 32) {
        gload16(Ag + k0,                    lA);
        gload16(Ag + k0 + (size_t)16 * lda, lA + 512);
        gload16(Bg + k0,                    lB);
        gload16(Bg + k0 + (size_t)16 * ldb, lB + 512);
        __syncthreads();

        short8 af[4], bf[4];
#pragma unroll
        for (int i = 0; i < 4; i++) af[i] = *(const short8*)(arow + i * 16 * 32);
#pragma unroll
        for (int j = 0; j < 4; j++) bf[j] = *(const short8*)(brow + j * 16 * 32);
#pragma unroll
        for (int i = 0; i < 4; i++)
#pragma unroll
            for (int j = 0; j < 4; j++)
                acc[i][j] = __builtin_amdgcn_mfma_f32_16x16x32_bf16(
                    af[i], bf[j], acc[i][j], 0, 0, 0);
        __syncthreads();
    }

    // D layout: col = lane&15, row = quad*4 + r   [verified m89/m91]
    const int mw = m0 + wr * 64;
    const int nw = n0 + wc * 64;
    const int rb = quad * 4;
#pragma unroll
    for (int i = 0; i < 4; i++) {
#pragma unroll
        for (int j = 0; j < 4; j++) {
            const int n = nw + j * 16 + r16;
#pragma unroll
            for (int r = 0; r < 4; r++) {
                const int m = mw + i * 16 + rb + r;
                float v = acc[i][j][r];
                if (OUTM == 2) {
                    v += bias[n];
                    v = (v > 20.f) ? v : log1pf(__expf(v));
                }
                if (OUTM == 4)
                    ((float*)Cv)[((size_t)blockIdx.z * M + m) * ldc + n] = v;
                else if (OUTM == 1)
                    ((float*)Cv)[(size_t)m * ldc + n] = v;
                else
                    ((u16*)Cv)[(size_t)m * ldc + n] = f2b(v);
            }
        }
    }
}

// =====================================================================
// reduce 4 split-K fp32 partials -> bf16 xdbl + fp32 bcf sideband
// =====================================================================
__global__ __launch_bounds__(256) void redk_gemm3(
    const float* __restrict__ part, u16* __restrict__ xdbl,
    float* __restrict__ bcf)
{
    const int t = blockIdx.x * 256 + threadIdx.x;   // over M*32
    const int n4 = (t & 31) * 4;
    const int m = t >> 5;
    const size_t stride = (size_t)M * NPAD;
    const float* p = part + (size_t)m * NPAD + n4;
    floatx4 acc = *(const floatx4*)(p)
                + *(const floatx4*)(p + stride)
                + *(const floatx4*)(p + 2 * stride)
                + *(const floatx4*)(p + 3 * stride);
    short4v ob;
#pragma unroll
    for (int j = 0; j < 4; j++) ob[j] = (short)f2b(acc[j]);
    *(short4v*)(xdbl + (size_t)m * NPAD + n4) = ob;
    if (n4 >= 64 && n4 < 96)
        *(floatx4*)(bcf + (size_t)m * 32 + (n4 - 64)) = acc;
}

// =====================================================================
__global__ __launch_bounds__(256) void cvt_f2b(
    const float* __restrict__ in, u16* __restrict__ out, int n)
{
    int i = blockIdx.x * blockDim.x + threadIdx.x;
    if (i < n) out[i] = f2b(in[i]);
}

// merged weight prep: W_in cvt | W_x pad | W_dt cvt | W_out cvt
__global__ __launch_bounds__(256) void prep_weights(
    const float* __restrict__ W_in, const float* __restrict__ W_x,
    const float* __restrict__ W_dt, const float* __restrict__ W_out,
    u16* __restrict__ wibf, u16* __restrict__ wxp,
    u16* __restrict__ wdtb, u16* __restrict__ woutb)
{
    constexpr int N1 = 2 * DI * DM;          // 4194304
    constexpr int N2 = NPAD * DI;            // 262144
    constexpr int N3 = DI * DTR;             // 131072
    int idx = blockIdx.x * blockDim.x + threadIdx.x;
    if (idx < N1) {
        wibf[idx] = f2b(W_in[idx]);
    } else if (idx < N1 + N2) {
        int i = idx - N1;
        int r = i >> 11, c = i & 2047;
        wxp[i] = (r < 96) ? f2b(W_x[r * 2048 + c]) : (u16)0;
    } else if (idx < N1 + N2 + N3) {
        int i = idx - N1 - N2;
        wdtb[i] = f2b(W_dt[i]);
    } else {
        int i = idx - N1 - N2 - N3;
        woutb[i] = f2b(W_out[i]);
    }
}

// =====================================================================
// Depthwise causal conv (K=4) + SiLU, vectorized.
// =====================================================================
__global__ __launch_bounds__(256) void conv_silu(
    const u16* __restrict__ xz, const float* __restrict__ conv_w,
    const float* __restrict__ conv_b, u16* __restrict__ xs)
{
    const int m = blockIdx.x;
    const int d0 = threadIdx.x * 8;
    const int l = m & (Ll - 1);

    float acc[8];
    {
        floatx4 cb0 = *(const floatx4*)(conv_b + d0);
        floatx4 cb1 = *(const floatx4*)(conv_b + d0 + 4);
#pragma unroll
        for (int j = 0; j < 4; j++) { acc[j] = cb0[j]; acc[4 + j] = cb1[j]; }
    }
    float w[8][KC];
#pragma unroll
    for (int jd = 0; jd < 8; jd++) {
        floatx4 wv = *(const floatx4*)(conv_w + (d0 + jd) * KC);
#pragma unroll
        for (int k = 0; k < KC; k++) w[jd][k] = wv[k];
    }
#pragma unroll
    for (int k = 0; k < KC; k++) {
        int li = l - (KC - 1) + k;
        if (li >= 0) {
            short8 xv = *(const short8*)(xz + (size_t)(m - (KC - 1) + k) * LDXZ + d0);
#pragma unroll
            for (int jd = 0; jd < 8; jd++)
                acc[jd] += b2f((u16)xv[jd]) * w[jd][k];
        }
    }
    short8 o;
#pragma unroll
    for (int jd = 0; jd < 8; jd++) {
        float s = acc[jd] / (1.f + __expf(-acc[jd]));
        o[jd] = (short)f2b(s);
    }
    *(short8*)(xs + (size_t)m * DI + d0) = o;
}

// =====================================================================
// Chunked selective scan.  One THREAD per (channel, chunk); 16 states in
// registers; coalesced dt/xs/z.  B/C panel (shared by the whole block:
// same (b, chunk)) staged into 16 KB LDS once, then broadcast ds_reads.
// Fast path (A_log = log(1..16), wave-uniform check): 1 exp + pow tree.
// =====================================================================
__global__ __launch_bounds__(256) void scan_p1(
    const u16* __restrict__ xzdt, const u16* __restrict__ xs,
    const float* __restrict__ bcf, const float* __restrict__ A_log,
    float* __restrict__ scr_P, float* __restrict__ scr_hend)
{
    __shared__ alignas(16) float bcs[LC * 32];   // 16 KB

    const int d = blockIdx.x * 256 + threadIdx.x;
    const int b = blockIdx.y;
    const int c = blockIdx.z;
    const int m0 = b * Ll + c * LC;

    // cooperative stage of the B/C panel (coalesced float4)
    {
        const float* bc_g = bcf + (size_t)m0 * 32;
#pragma unroll
        for (int j = 0; j < 4; j++) {
            int idx = j * 1024 + threadIdx.x * 4;
            *(floatx4*)(bcs + idx) = *(const floatx4*)(bc_g + idx);
        }
    }

    const float ad0 = -__expf(A_log[0]);
    float adl[DS];
    bool fast = true;
#pragma unroll
    for (int s = 0; s < DS; s++) {
        float av = -__expf(A_log[s]);
        adl[s] = av;
        float kr = (float)(s + 1);
        if (fabsf(av / ad0 - kr) > 1e-4f * kr) fast = false;
    }

    const u16* dt_p = xzdt + (size_t)m0 * LDXZ + d;
    const u16* xs_p = xs + (size_t)m0 * DI + d;

    float h[DS] = {};
    float P[DS];
#pragma unroll
    for (int s = 0; s < DS; s++) P[s] = 1.f;
    float sdt = 0.f;

    __syncthreads();

    u16 dt_c = dt_p[0];
    u16 xs_c = xs_p[0];

    if (fast) {
        for (int l = 0; l < LC; l++) {
            u16 dt_n = dt_p[LDXZ];           // benign over-read at l=LC-1
            u16 xs_n = xs_p[DI];
            const float* bl = bcs + l * 32;
            floatx4 B0 = *(const floatx4*)(bl);
            floatx4 B1 = *(const floatx4*)(bl + 4);
            floatx4 B2 = *(const floatx4*)(bl + 8);
            floatx4 B3 = *(const floatx4*)(bl + 12);

            float dtv = b2f(dt_c);
            float xv  = b2f(xs_c);
            float bx = dtv * xv;
            sdt += dtv;
            float aa[DS];
            pow_tree(__expf(dtv * ad0), aa);
#pragma unroll
            for (int s = 0; s < DS; s++) {
                float Bv = (s < 4) ? B0[s] : (s < 8) ? B1[s - 4]
                         : (s < 12) ? B2[s - 8] : B3[s - 12];
                h[s] = aa[s] * h[s] + bx * Bv;
            }
            dt_c = dt_n; xs_c = xs_n;
            dt_p += LDXZ; xs_p += DI;
        }
        pow_tree(__expf(ad0 * sdt), P);
    } else {
        for (int l = 0; l < LC; l++) {
            u16 dt_n = dt_p[LDXZ];
            u16 xs_n = xs_p[DI];
            const float* bl = bcs + l * 32;
            floatx4 B0 = *(const floatx4*)(bl);
            floatx4 B1 = *(const floatx4*)(bl + 4);
            floatx4 B2 = *(const floatx4*)(bl + 8);
            floatx4 B3 = *(const floatx4*)(bl + 12);

            float dtv = b2f(dt_c);
            float xv  = b2f(xs_c);
            float bx = dtv * xv;
#pragma unroll
            for (int s = 0; s < DS; s++) {
                float Bv = (s < 4) ? B0[s] : (s < 8) ? B1[s - 4]
                         : (s < 12) ? B2[s - 8] : B3[s - 12];
                float a = __expf(dtv * adl[s]);
                h[s] = a * h[s] + bx * Bv;
                P[s] *= a;
            }
            dt_c = dt_n; xs_c = xs_n;
            dt_p += LDXZ; xs_p += DI;
        }
    }

    const size_t base = ((size_t)(b * NCHUNK + c) * DI + d) * DS;
#pragma unroll
    for (int s = 0; s < DS; s += 4) {
        floatx4 pv = {P[s], P[s+1], P[s+2], P[s+3]};
        floatx4 hv = {h[s], h[s+1], h[s+2], h[s+3]};
        *(floatx4*)(scr_P + base + s)    = pv;
        *(floatx4*)(scr_hend + base + s) = hv;
    }
}

__global__ __launch_bounds__(256) void scan_p2(
    float* __restrict__ scr_P, const float* __restrict__ scr_hend)
{
    const int t = blockIdx.x * 256 + threadIdx.x;   // (b, d, s)
    const int s = t & 15;
    const int d = (t >> 4) & (DI - 1);
    const int b = t >> 15;

    float hin = 0.f;
    for (int c = 0; c < NCHUNK; c++) {
        const size_t base = ((size_t)(b * NCHUNK + c) * DI + d) * DS + s;
        float p = scr_P[base];
        float he = scr_hend[base];
        scr_P[base] = hin;
        hin = p * hin + he;
    }
}

__global__ __launch_bounds__(256) void scan_p3(
    const u16* __restrict__ xz, const u16* xs, const float* __restrict__ bcf,
    const float* __restrict__ scr_hin, const float* __restrict__ A_log,
    const float* __restrict__ Dvec, u16* yg)
{
    __shared__ alignas(16) float bcs[LC * 32];   // 16 KB

    const int d = blockIdx.x * 256 + threadIdx.x;
    const int b = blockIdx.y;
    const int c = blockIdx.z;
    const int m0 = b * Ll + c * LC;

    {
        const float* bc_g = bcf + (size_t)m0 * 32;
#pragma unroll
        for (int j = 0; j < 4; j++) {
            int idx = j * 1024 + threadIdx.x * 4;
            *(floatx4*)(bcs + idx) = *(const floatx4*)(bc_g + idx);
        }
    }

    const float ad0 = -__expf(A_log[0]);
    float adl[DS];
    bool fast = true;
#pragma unroll
    for (int s = 0; s < DS; s++) {
        float av = -__expf(A_log[s]);
        adl[s] = av;
        float kr = (float)(s + 1);
        if (fabsf(av / ad0 - kr) > 1e-4f * kr) fast = false;
    }
    const float Dd = Dvec[d];

    const u16* dt_p = xz + (size_t)m0 * LDXZ + d;          // xr half = dt
    const u16* z_p  = xz + (size_t)m0 * LDXZ + 2048 + d;   // z half
    const u16* xs_p = xs + (size_t)m0 * DI + d;
    u16* yg_p = yg + (size_t)m0 * DI + d;

    float h[DS];
    const size_t base = ((size_t)(b * NCHUNK + c) * DI + d) * DS;
#pragma unroll
    for (int s = 0; s < DS; s += 4) {
        floatx4 hv = *(const floatx4*)(scr_hin + base + s);
        h[s] = hv[0]; h[s+1] = hv[1]; h[s+2] = hv[2]; h[s+3] = hv[3];
    }

    __syncthreads();

    u16 dt_c = dt_p[0];
    u16 xs_c = xs_p[0];
    u16 z_c  = z_p[0];

    for (int l = 0; l < LC; l++) {
        u16 dt_n = dt_p[LDXZ];
        u16 xs_n = xs_p[DI];
        u16 z_n  = z_p[LDXZ];
        const float* bl = bcs + l * 32;
        floatx4 Bq[4], Cq[4];
#pragma unroll
        for (int q = 0; q < 4; q++) {
            Bq[q] = *(const floatx4*)(bl + q * 4);
            Cq[q] = *(const floatx4*)(bl + 16 + q * 4);
        }

        float dtv = b2f(dt_c);
        float xv  = b2f(xs_c);
        float bx = dtv * xv;
        float aa[DS];
        if (fast) {
            pow_tree(__expf(dtv * ad0), aa);
        } else {
#pragma unroll
            for (int s = 0; s < DS; s++) aa[s] = __expf(dtv * adl[s]);
        }
        float y0 = 0.f, y1 = 0.f, y2 = 0.f, y3 = 0.f;
#pragma unroll
        for (int q = 0; q < 4; q++) {
#pragma unroll
            for (int j = 0; j < 4; j++) {
                int s = q * 4 + j;
                h[s] = aa[s] * h[s] + bx * Bq[q][j];
            }
        }
#pragma unroll
        for (int j = 0; j < 4; j++) {
            y0 += h[j] * Cq[0][j];
            y1 += h[4 + j] * Cq[1][j];
            y2 += h[8 + j] * Cq[2][j];
            y3 += h[12 + j] * Cq[3][j];
        }
        float yt = ((y0 + y1) + (y2 + y3)) + Dd * xv;
        float zv = b2f(z_c);
        float g = zv / (1.f + __expf(-zv));
        yg_p[0] = f2b(yt * g);

        dt_c = dt_n; xs_c = xs_n; z_c = z_n;
        dt_p += LDXZ; xs_p += DI; z_p += LDXZ; yg_p += DI;
    }
}

// =====================================================================
extern "C" void kernel_launch(void* const* d_in, const int* in_sizes, int n_in,
                              void* d_out, int out_size, void* d_ws, size_t ws_size,
                              hipStream_t stream)
{
    const float* x      = (const float*)d_in[0];   // (B,L,DM)
    const float* W_in   = (const float*)d_in[1];   // (2*DI, DM)
    const float* conv_w = (const float*)d_in[2];   // (DI, KC)
    const float* conv_b = (const float*)d_in[3];   // (DI,)
    const float* A_log  = (const float*)d_in[4];   // (DS,)
    const float* Dvec   = (const float*)d_in[5];   // (DI,)
    const float* W_x    = (const float*)d_in[6];   // (96, DI)
    const float* W_dt   = (const float*)d_in[7];   // (DI, DTR)
    const float* b_dt   = (const float*)d_in[8];   // (DI,)
    const float* W_out  = (const float*)d_in[9];   // (DM, DI)

    // ---- workspace arena (bf16 u16 elements), ~133 MB total ----
    u16* ws = (u16*)d_ws;
    u16* xz    = ws;                 ws += (size_t)M * LDXZ;     // 67.1 MB (xr|z; xr half reused for dt)
    u16* xs    = ws;                 ws += (size_t)M * DI;       // 33.55 MB (yg in-place)
    u16* xbf   = ws;                 ws += (size_t)M * DM;       // 16.78 MB (x bf16 -> split-K parts -> scan scratch)
    u16* wibf  = ws;                 ws += (size_t)2 * DI * DM;  // 8.39 MB (reused as bcf)
    u16* wxp   = ws;                 ws += (size_t)NPAD * DI;    // 0.52 MB
    u16* wdtb  = ws;                 ws += (size_t)DI * DTR;     // 0.26 MB
    u16* woutb = ws;                 ws += (size_t)DM * DI;      // 4.19 MB
    u16* xdbl  = ws;                 ws += (size_t)M * NPAD;     // 2.10 MB
    u16* yg    = xs;                 // in-place
    float* part     = (float*)xbf;   // split-K partials (xbf dead after GEMM1)
    float* scr_P    = (float*)xbf;   // scan scratch (after reduce consumed parts)
    float* scr_hend = scr_P + (size_t)Bb * NCHUNK * DI * DS;
    float* bcf      = (float*)wibf;  // 1.05 MB (wibf dead after GEMM1)

    // 0) operand conversions (x + merged weight prep)
    cvt_f2b<<<(M * DM) / 256, 256, 0, stream>>>(x, xbf, M * DM);
    {
        constexpr int NTOT = 2 * DI * DM + NPAD * DI + DI * DTR + DM * DI;
        prep_weights<<<NTOT / 256, 256, 0, stream>>>(
            W_in, W_x, W_dt, W_out, wibf, wxp, wdtb, woutb);
    }

    // 1) xz = x @ W_in^T   (8192 x 4096, K=1024) — merged xr|z
    gemm_bt<0><<<dim3(LDXZ / 128, M / 128), 256, 0, stream>>>(
        xbf, wibf, xz, nullptr, DM, DM, DM, LDXZ);

    // 2) conv + silu -> xs   (reads xr half of xz)
    conv_silu<<<M, 256, 0, stream>>>(xz, conv_w, conv_b, xs);

    // 3) x_dbl = xs @ wxp^T, split-K x4 -> fp32 parts, then reduce
    gemm_bt<4><<<dim3(1, M / 128, 4), 256, 0, stream>>>(
        xs, wxp, part, nullptr, DI / 4, DI, DI, NPAD);
    redk_gemm3<<<(M * 32) / 256, 256, 0, stream>>>(part, xdbl, bcf);

    // 4) dt = softplus(x_dbl[:, :64] @ W_dt^T + b_dt) -> xr half of xz
    gemm_bt<2><<<dim3(DI / 128, M / 128), 256, 0, stream>>>(
        xdbl, wdtb, xz, b_dt, DTR, NPAD, DTR, LDXZ);

    // 5) chunked scan
    scan_p1<<<dim3(DI / 256, Bb, NCHUNK), 256, 0, stream>>>(
        xz, xs, bcf, A_log, scr_P, scr_hend);
    scan_p2<<<(Bb * DI * DS) / 256, 256, 0, stream>>>(scr_P, scr_hend);
    scan_p3<<<dim3(DI / 256, Bb, NCHUNK), 256, 0, stream>>>(
        xz, xs, bcf, scr_P, A_log, Dvec, yg);

    // 6) out = yg @ W_out^T   (8192 x 1024, K=2048), fp32 store
    gemm_bt<1><<<dim3(DM / 128, M / 128), 256, 0, stream>>>(
        yg, woutb, d_out, nullptr, DI, DI, DI, DM);
}